// Round 1
// 315.076 us; speedup vs baseline: 1.2743x; 1.2743x over previous
//
#include <hip/hip_runtime.h>
#include <stdint.h>

typedef float  floatx4 __attribute__((ext_vector_type(4)));
typedef int    intx8   __attribute__((ext_vector_type(8)));   // 32 fp8 bytes = 8 VGPRs

#define AS1 __attribute__((address_space(1)))
#define AS3 __attribute__((address_space(3)))

// ---------------------------------------------------------------------------
// helpers
// ---------------------------------------------------------------------------
// Round v (pre-clamped to [-448,448]) to the e4m3fn grid, RNE. Exact:
// v*rstep is exact (rstep = 2^k), rintf is RNE, *step is exact.
__device__ __forceinline__ float quant_e4m3_value(float v) {
  float av = fabsf(v);
  float step, rstep;
  if (av < 0.015625f) {            // below 2^-6: e4m3 subnormal region
    step  = 0.001953125f;          // 2^-9
    rstep = 512.0f;
  } else {
    uint32_t e = __float_as_uint(av) >> 23;            // biased exponent
    step  = __uint_as_float((e - 3u) << 23);           // 2^(E-3)
    rstep = __uint_as_float((257u - e) << 23);         // 2^(3-E)
  }
  return rintf(v * rstep) * step;
}

// Encode an f32 value that is EXACTLY on the e4m3fn grid into its byte.
// Pure bit math, no rounding: field = biased_exp-120, mantissa = top 3 bits.
__device__ __forceinline__ uint32_t enc_e4m3(float v) {
  uint32_t u = __float_as_uint(v);
  uint32_t s = (u >> 24) & 0x80u;
  float av = fabsf(v);
  uint32_t b;
  if (av < 0.015625f) {                       // subnormal: m = av * 2^9 (exact int 0..7)
    b = s | (uint32_t)(av * 512.0f);
  } else {
    uint32_t e = ((u >> 23) & 0xffu) - 120u;  // e4m3 exponent field 1..15
    uint32_t m = (u >> 20) & 7u;
    b = s | (e << 3) | m;
  }
  return b;
}

// Decode e4m3fn byte -> f32 (exact; clipped qweight has no NaN).
__device__ __forceinline__ float dec_e4m3(uint32_t b) {
  uint32_t s = (b & 0x80u) << 24;
  uint32_t e = (b >> 3) & 15u, m = b & 7u;
  float mag;
  if (e == 0u) mag = (float)m * 0.001953125f;                         // m*2^-9
  else         mag = __uint_as_float(((e + 120u) << 23) | (m << 20)); // (1+m/8)*2^(e-7)
  return __uint_as_float(s | __float_as_uint(mag));
}

// ---------------------------------------------------------------------------
// Kernel 0: detect qweight storage format. One wave, graph-safe.
//   mode 2: f32 holding e4m3 values  -> every uint32 has bits[19:0]==0
//   mode 1: bf16 holding e4m3 values -> every uint16 has bits[3:0]==0
//   mode 0: raw fp8 bytes            -> neither
// ---------------------------------------------------------------------------
__global__ void detect_mode_kernel(const uint32_t* __restrict__ qw,
                                   int* __restrict__ mode) {
  int t = threadIdx.x;  // 64 threads
  uint32_t w0 = qw[t], w1 = qw[t + 64];
  bool a = ((w0 & 0xFFFFFu) == 0u) && ((w1 & 0xFFFFFu) == 0u);
  uint32_t nib = (w0 | (w0 >> 16) | w1 | (w1 >> 16)) & 0xFu;
  bool b = (nib == 0u);
  unsigned long long ba = __ballot(a);
  unsigned long long bb = __ballot(b);
  if (t == 0) mode[0] = (ba == ~0ull) ? 2 : ((bb == ~0ull) ? 1 : 0);
}

// ---------------------------------------------------------------------------
// Kernel 1: quantize x (f32): clip(x/s, +-448) -> e4m3 RNE -> raw byte.
// float4 in (16B), uint32 out (4B) per thread.
// ---------------------------------------------------------------------------
__global__ __launch_bounds__(256) void quantize_x_kernel(
    const float4* __restrict__ x, const float* __restrict__ s_ptr,
    uint32_t* __restrict__ q, int n4) {
  int i = blockIdx.x * 256 + threadIdx.x;
  if (i >= n4) return;
  const float s = s_ptr[0];
  float4 v = x[i];
  // IEEE division to match reference x / input_scale
  float a0 = quant_e4m3_value(fminf(fmaxf(v.x / s, -448.0f), 448.0f));
  float a1 = quant_e4m3_value(fminf(fmaxf(v.y / s, -448.0f), 448.0f));
  float a2 = quant_e4m3_value(fminf(fmaxf(v.z / s, -448.0f), 448.0f));
  float a3 = quant_e4m3_value(fminf(fmaxf(v.w / s, -448.0f), 448.0f));
  q[i] = enc_e4m3(a0) | (enc_e4m3(a1) << 8) | (enc_e4m3(a2) << 16) |
         (enc_e4m3(a3) << 24);
}

// ---------------------------------------------------------------------------
// Kernel 2: weights -> raw e4m3 bytes [N][K], per detected mode.
// Branch is wave-uniform (mode is a device-memory scalar).
// ---------------------------------------------------------------------------
__global__ __launch_bounds__(256) void prep_w_kernel(
    const uint8_t* __restrict__ qw, const int* __restrict__ mode,
    uint32_t* __restrict__ w8, int n4) {
  int i = blockIdx.x * 256 + threadIdx.x;
  if (i >= n4) return;
  int m = mode[0];
  uint32_t o;
  if (m == 1) {                       // bf16 storage: decode (<<16 exact), encode
    ushort4 u = ((const ushort4*)qw)[i];
    o = enc_e4m3(__uint_as_float((uint32_t)u.x << 16)) |
        (enc_e4m3(__uint_as_float((uint32_t)u.y << 16)) << 8) |
        (enc_e4m3(__uint_as_float((uint32_t)u.z << 16)) << 16) |
        (enc_e4m3(__uint_as_float((uint32_t)u.w << 16)) << 24);
  } else if (m == 2) {                // f32 storage
    float4 v = ((const float4*)qw)[i];
    o = enc_e4m3(v.x) | (enc_e4m3(v.y) << 8) | (enc_e4m3(v.z) << 16) |
        (enc_e4m3(v.w) << 24);
  } else {                            // raw fp8 bytes: straight copy
    o = ((const uint32_t*)qw)[i];
  }
  w8[i] = o;
}

// ---------------------------------------------------------------------------
// Kernel 3: MX-scaled fp8 GEMM  C[m,n] = sc*sum_k A[m,k]*B[n,k] + bias[n].
// 128x128 tile, BK=128 (bytes), 256 thr / 4 waves, wave = 64x64 via 4x4 grid
// of mfma_scale_f32_16x16x128_f8f6f4 with constant 1.0 (e8m0=127) scales.
// Staging via global_load_lds width=16 (linear LDS, lane-contiguous dest).
// Structure = m97/m148 (2-barrier loop) -> measured 1628 TF at this shape.
// ---------------------------------------------------------------------------
__global__ __launch_bounds__(256) void gemm_fp8_kernel(
    const uint8_t* __restrict__ A, const uint8_t* __restrict__ B,
    const float* __restrict__ wscale, const float* __restrict__ iscale,
    const float* __restrict__ bias, float* __restrict__ out,
    int M, int N, int K) {
  __shared__ uint8_t lsA[128 * 128];  // 16 KB, fp8 bytes, row stride 128
  __shared__ uint8_t lsB[128 * 128];  // 16 KB

  const int tid  = threadIdx.x;
  const int wave = tid >> 6;
  const int lane = tid & 63;
  const int bm = blockIdx.y;
  const int bn = blockIdx.x;

  const int wm = (wave & 1) * 64;
  const int wn = (wave >> 1) * 64;

  // staging: thread t = w*64+l handles 16B chunk (t&7) of row (t>>3) + 32*it
  // LDS linear offset = it*4096 + w*1024 + l*16  -> lane-contiguous per wave,
  // as global_load_lds requires (wave-uniform base + lane*16).
  const int srow   = tid >> 3;         // 0..31
  const int schunk = (tid & 7) * 16;   // byte offset within 128B row

  const uint8_t* gA = A + (size_t)(bm * 128 + srow) * K + schunk;
  const uint8_t* gB = B + (size_t)(bn * 128 + srow) * K + schunk;
  uint8_t* lA = &lsA[srow * 128 + schunk];
  uint8_t* lB = &lsB[srow * 128 + schunk];

  const int r15  = lane & 15;
  const int quad = lane >> 4;

  floatx4 acc[4][4];
#pragma unroll
  for (int i = 0; i < 4; ++i)
#pragma unroll
    for (int j = 0; j < 4; ++j) acc[i][j] = (floatx4){0.f, 0.f, 0.f, 0.f};

  for (int k0 = 0; k0 < K; k0 += 128) {
    __syncthreads();  // previous iteration's LDS reads done
#pragma unroll
    for (int it = 0; it < 4; ++it) {
      __builtin_amdgcn_global_load_lds(
          (const AS1 void*)(gA + k0 + (size_t)it * 32 * K),
          (AS3 void*)(lA + it * 32 * 128), 16, 0, 0);
      __builtin_amdgcn_global_load_lds(
          (const AS1 void*)(gB + k0 + (size_t)it * 32 * K),
          (AS3 void*)(lB + it * 32 * 128), 16, 0, 0);
    }
    __syncthreads();  // staging visible (compiler drains vmcnt before barrier)

    // fragments: lane holds row (l&15), k-bytes [quad*32, quad*32+32)
    intx8 af[4], bf[4];
#pragma unroll
    for (int mi = 0; mi < 4; ++mi)
      af[mi] = *(const intx8*)(&lsA[(wm + mi * 16 + r15) * 128 + quad * 32]);
#pragma unroll
    for (int ni = 0; ni < 4; ++ni)
      bf[ni] = *(const intx8*)(&lsB[(wn + ni * 16 + r15) * 128 + quad * 32]);

#pragma unroll
    for (int mi = 0; mi < 4; ++mi)
#pragma unroll
      for (int ni = 0; ni < 4; ++ni)
        acc[mi][ni] = __builtin_amdgcn_mfma_scale_f32_16x16x128_f8f6f4(
            af[mi], bf[ni], acc[mi][ni],
            0 /*cbsz: A fmt fp8*/, 0 /*blgp: B fmt fp8*/,
            0, 127 /*scale_a = 1.0 (e8m0)*/, 0, 127 /*scale_b = 1.0*/);
  }

  // epilogue: C/D layout col=lane&15 (n), row=quad*4+reg (m) [m89/m91,
  // shape-determined for f8f6f4 per m127/m128]
  const float sc = wscale[0] * iscale[0];
  const int rq = quad * 4;
#pragma unroll
  for (int ni = 0; ni < 4; ++ni) {
    const int col = bn * 128 + wn + ni * 16 + r15;
    const float bv = bias[col];
#pragma unroll
    for (int mi = 0; mi < 4; ++mi) {
      const int row = bm * 128 + wm + mi * 16 + rq;
      float* o = out + (size_t)row * N + col;
#pragma unroll
      for (int r = 0; r < 4; ++r)
        o[(size_t)r * N] = acc[mi][ni][r] * sc + bv;
    }
  }
}

// ---------------------------------------------------------------------------
extern "C" void kernel_launch(void* const* d_in, const int* in_sizes, int n_in,
                              void* d_out, int out_size, void* d_ws,
                              size_t ws_size, hipStream_t stream) {
  // Storage (deduced earlier sessions): x f32, qweight bf16 holding e4m3
  // values (runtime re-checked every call), wscale/iscale/bias f32, out f32.
  const float*   x      = (const float*)d_in[0];   // f32 [M,K]
  const uint8_t* qw     = (const uint8_t*)d_in[1]; // detected [N,K]
  const float*   wscale = (const float*)d_in[2];   // f32 scalar
  const float*   iscale = (const float*)d_in[3];   // f32 scalar
  const float*   bias   = (const float*)d_in[4];   // f32 [N]
  float*         out    = (float*)d_out;

  const int N = in_sizes[4];          // 2048 (element counts)
  const int K = in_sizes[1] / N;      // 2048
  const int M = in_sizes[0] / K;      // 16384

  // ws layout: [0, M*K) qx fp8 ; [+, N*K) w8 fp8 ; [+, 4) mode flag
  uint8_t* qx   = (uint8_t*)d_ws;
  uint8_t* w8   = qx + (size_t)M * K;
  int*     mode = (int*)(w8 + (size_t)N * K);

  detect_mode_kernel<<<1, 64, 0, stream>>>((const uint32_t*)qw, mode);

  const int nx4 = in_sizes[0] / 4;
  quantize_x_kernel<<<(nx4 + 255) / 256, 256, 0, stream>>>(
      (const float4*)x, iscale, (uint32_t*)qx, nx4);

  const int nw4 = in_sizes[1] / 4;
  prep_w_kernel<<<(nw4 + 255) / 256, 256, 0, stream>>>(
      qw, mode, (uint32_t*)w8, nw4);

  dim3 grid(N / 128, M / 128);
  gemm_fp8_kernel<<<grid, 256, 0, stream>>>(qx, w8, wscale, iscale, bias,
                                            out, M, N, K);
}

// Round 3
// 313.658 us; speedup vs baseline: 1.2800x; 1.0045x over previous
//
#include <hip/hip_runtime.h>
#include <stdint.h>

typedef float  floatx4 __attribute__((ext_vector_type(4)));
typedef int    intx4   __attribute__((ext_vector_type(4)));
typedef int    intx8   __attribute__((ext_vector_type(8)));   // 32 fp8 bytes

#define AS1 __attribute__((address_space(1)))
#define AS3 __attribute__((address_space(3)))

// ---------------------------------------------------------------------------
// helpers
// ---------------------------------------------------------------------------
// Round v (pre-clamped to [-448,448]) to the e4m3fn grid, RNE. Exact.
__device__ __forceinline__ float quant_e4m3_value(float v) {
  float av = fabsf(v);
  float step, rstep;
  if (av < 0.015625f) {            // below 2^-6: e4m3 subnormal region
    step  = 0.001953125f;          // 2^-9
    rstep = 512.0f;
  } else {
    uint32_t e = __float_as_uint(av) >> 23;            // biased exponent
    step  = __uint_as_float((e - 3u) << 23);           // 2^(E-3)
    rstep = __uint_as_float((257u - e) << 23);         // 2^(3-E)
  }
  return rintf(v * rstep) * step;
}

// Encode an f32 value EXACTLY on the e4m3fn grid into its byte (pure bit math).
__device__ __forceinline__ uint32_t enc_e4m3(float v) {
  uint32_t u = __float_as_uint(v);
  uint32_t s = (u >> 24) & 0x80u;
  float av = fabsf(v);
  uint32_t b;
  if (av < 0.015625f) {                       // subnormal: m = av*2^9 (0..7)
    b = s | (uint32_t)(av * 512.0f);
  } else {
    uint32_t e = ((u >> 23) & 0xffu) - 120u;  // e4m3 exponent field 1..15
    uint32_t m = (u >> 20) & 7u;
    b = s | (e << 3) | m;
  }
  return b;
}

// ---------------------------------------------------------------------------
// Kernel 1: quantize x (f32): clip(x/s, +-448) -> e4m3 RNE -> raw byte.
// ---------------------------------------------------------------------------
__global__ __launch_bounds__(256) void quantize_x_kernel(
    const float4* __restrict__ x, const float* __restrict__ s_ptr,
    uint32_t* __restrict__ q, int n4) {
  int i = blockIdx.x * 256 + threadIdx.x;
  if (i >= n4) return;
  const float s = s_ptr[0];
  float4 v = x[i];
  float a0 = quant_e4m3_value(fminf(fmaxf(v.x / s, -448.0f), 448.0f));
  float a1 = quant_e4m3_value(fminf(fmaxf(v.y / s, -448.0f), 448.0f));
  float a2 = quant_e4m3_value(fminf(fmaxf(v.z / s, -448.0f), 448.0f));
  float a3 = quant_e4m3_value(fminf(fmaxf(v.w / s, -448.0f), 448.0f));
  q[i] = enc_e4m3(a0) | (enc_e4m3(a1) << 8) | (enc_e4m3(a2) << 16) |
         (enc_e4m3(a3) << 24);
}

// ---------------------------------------------------------------------------
// Kernel 2: weights -> raw e4m3 bytes [N][K]. Mode detection inlined per
// block (first 512B of qw, L2-hot; all waves agree -> uniform branch).
//   mode 2: f32 holding e4m3 values; mode 1: bf16; mode 0: raw fp8 bytes.
// ---------------------------------------------------------------------------
__global__ __launch_bounds__(256) void prep_w_kernel(
    const uint8_t* __restrict__ qw, uint32_t* __restrict__ w8, int n4) {
  const uint32_t* q32 = (const uint32_t*)qw;
  int lane = threadIdx.x & 63;
  uint32_t w0 = q32[lane], w1 = q32[lane + 64];
  bool fa = ((w0 & 0xFFFFFu) == 0u) && ((w1 & 0xFFFFFu) == 0u);
  uint32_t nib = (w0 | (w0 >> 16) | w1 | (w1 >> 16)) & 0xFu;
  unsigned long long ba = __ballot(fa);
  unsigned long long bb = __ballot(nib == 0u);
  int m = (ba == ~0ull) ? 2 : ((bb == ~0ull) ? 1 : 0);

  int i = blockIdx.x * 256 + threadIdx.x;
  if (i >= n4) return;
  uint32_t o;
  if (m == 1) {                       // bf16 storage: <<16 decode (exact), encode
    ushort4 u = ((const ushort4*)qw)[i];
    o = enc_e4m3(__uint_as_float((uint32_t)u.x << 16)) |
        (enc_e4m3(__uint_as_float((uint32_t)u.y << 16)) << 8) |
        (enc_e4m3(__uint_as_float((uint32_t)u.z << 16)) << 16) |
        (enc_e4m3(__uint_as_float((uint32_t)u.w << 16)) << 24);
  } else if (m == 2) {                // f32 storage
    float4 v = ((const float4*)qw)[i];
    o = enc_e4m3(v.x) | (enc_e4m3(v.y) << 8) | (enc_e4m3(v.z) << 16) |
        (enc_e4m3(v.w) << 24);
  } else {                            // raw fp8 bytes: straight copy
    o = ((const uint32_t*)qw)[i];
  }
  w8[i] = o;
}

// ---------------------------------------------------------------------------
// Kernel 3: MX-scaled fp8 GEMM, deep pipeline, LDS = exactly 128 KiB.
//   Tile BM=256 x BN=128, BK=128 bytes. 512 thr = 8 waves (4M x 2N);
//   per-wave C = 64x64 = 4x4 frags of mfma_scale_f32_16x16x128_f8f6f4,
//   constant e8m0 scale 127 (=1.0); wscale*iscale in epilogue.
//   A: tri-buffered (3 x 32K), prefetch depth 2 (HBM stream, ~900cy).
//   B: double-buffered (2 x 16K), prefetch depth 1 (L2-hot panel).
//   Per tile: issue B(t+1) THEN A(t+2); end-of-tile s_waitcnt vmcnt(4)
//   leaves only A(t+2) in flight => A(t+1)+B(t+1) complete. One raw
//   s_barrier per tile (WAR-safe: recycled buffers were last ds_read
//   before the PREVIOUS barrier, since reads feed MFMAs pre-barrier).
//   T2 chunk-XOR swizzle (linear gload_lds dest + pre-swizzled global
//   source + swizzled ds_read, rule 21), T5 setprio, T1 XCD swizzle.
// ---------------------------------------------------------------------------
__global__ __launch_bounds__(512) void gemm_fp8_kernel(
    const uint8_t* __restrict__ A, const uint8_t* __restrict__ B,
    const float* __restrict__ wscale, const float* __restrict__ iscale,
    const float* __restrict__ bias, float* __restrict__ out,
    int M, int N, int K) {
  __shared__ uint8_t lds[131072];      // 3*32K (A) + 2*16K (B) = 128 KiB

  const int tid  = threadIdx.x;
  const int lane = tid & 63;
  const int wave = tid >> 6;

  // T1: XCD swizzle, contiguous flat-chunks per XCD (nwg = 1024, %8 == 0)
  const int nbx = gridDim.x;                     // N/128
  const int nwg = nbx * gridDim.y;
  int flat = blockIdx.y * nbx + blockIdx.x;
  flat = (flat & 7) * (nwg >> 3) + (flat >> 3);
  const int bm = flat / nbx;
  const int bn = flat - bm * nbx;

  const int wm_i = wave >> 1;      // 0..3
  const int wn_i = wave & 1;       // 0..1
  const int r15  = lane & 15;
  const int quad = lane >> 4;

  // ----- staging descriptors -----
  // slot s -> row = s>>3, LDS chunkpos p = s&7, global chunk = p ^ (row&7)
  const uint8_t* asrc[4]; uint32_t adst[4];   // A: 4 slots (rows 0..255)
  const uint8_t* bsrc[2]; uint32_t bdst[2];   // B: 2 slots (rows 0..127)
#pragma unroll
  for (int j = 0; j < 4; ++j) {
    const int s = tid + j * 512, row = s >> 3, p = s & 7;
    asrc[j] = A + (size_t)(bm * 256 + row) * K + ((p ^ (row & 7)) << 4);
    adst[j] = (uint32_t)s << 4;               // offset within an A buffer
  }
#pragma unroll
  for (int j = 0; j < 2; ++j) {
    const int s = tid + j * 512, row = s >> 3, p = s & 7;
    bsrc[j] = B + (size_t)(bn * 128 + row) * K + ((p ^ (row & 7)) << 4);
    bdst[j] = (uint32_t)s << 4;               // offset within a B buffer
  }

#define STAGE_A(j, kbyte, ab)                                                  \
  __builtin_amdgcn_global_load_lds(                                            \
      (const AS1 void*)(asrc[j] + (kbyte)),                                    \
      (AS3 void*)(&lds[(ab) * 32768u + adst[j]]), 16, 0, 0)
#define STAGE_B(j, kbyte, bb)                                                  \
  __builtin_amdgcn_global_load_lds(                                            \
      (const AS1 void*)(bsrc[j] + (kbyte)),                                    \
      (AS3 void*)(&lds[98304u + (bb) * 16384u + bdst[j]]), 16, 0, 0)

  floatx4 acc[4][4];
#pragma unroll
  for (int i = 0; i < 4; ++i)
#pragma unroll
    for (int j = 0; j < 4; ++j) acc[i][j] = (floatx4){0.f, 0.f, 0.f, 0.f};

  const int T = K >> 7;              // K-tiles of 128 bytes

  // ----- prologue: B(0), A(0) [tile 0], A(1) [depth-2 head start] -----
  STAGE_B(0, 0, 0); STAGE_B(1, 0, 0);
  STAGE_A(0, 0, 0); STAGE_A(1, 0, 0); STAGE_A(2, 0, 0); STAGE_A(3, 0, 0);
  if (T > 1) {
    STAGE_A(0, 128, 1); STAGE_A(1, 128, 1);
    STAGE_A(2, 128, 1); STAGE_A(3, 128, 1);
    asm volatile("s_waitcnt vmcnt(4)" ::: "memory");   // B0,A0 landed
  } else {
    asm volatile("s_waitcnt vmcnt(0)" ::: "memory");
  }
  __builtin_amdgcn_sched_barrier(0);
  __builtin_amdgcn_s_barrier();

  int ab = 0, bb = 0;
  for (int t = 0; t < T; ++t) {
    const uint8_t* lA = &lds[ab * 32768u];
    const uint8_t* lB = &lds[98304u + bb * 16384u];

    // prefetch: B(t+1) first (must be older than A(t+2) for vmcnt(4))
    if (t + 1 < T) {
      const int kb = (t + 1) << 7;
      STAGE_B(0, kb, bb ^ 1); STAGE_B(1, kb, bb ^ 1);
    }
    if (t + 2 < T) {
      int a2 = ab + 2; if (a2 >= 3) a2 -= 3;
      const int kb = (t + 2) << 7;
      STAGE_A(0, kb, a2); STAGE_A(1, kb, a2);
      STAGE_A(2, kb, a2); STAGE_A(3, kb, a2);
    }

    // fragment loads (T2-swizzled chunk addresses; bank-balanced)
    intx8 af[4], bf[4];
#pragma unroll
    for (int i = 0; i < 4; ++i) {
      const int r = wm_i * 64 + i * 16 + r15, k8 = r & 7;
      intx4 lo = *(const intx4*)&lA[r * 128 + (((quad * 2)     ^ k8) << 4)];
      intx4 hi = *(const intx4*)&lA[r * 128 + (((quad * 2 + 1) ^ k8) << 4)];
      af[i] = __builtin_shufflevector(lo, hi, 0, 1, 2, 3, 4, 5, 6, 7);
    }
#pragma unroll
    for (int i = 0; i < 4; ++i) {
      const int r = wn_i * 64 + i * 16 + r15, k8 = r & 7;
      intx4 lo = *(const intx4*)&lB[r * 128 + (((quad * 2)     ^ k8) << 4)];
      intx4 hi = *(const intx4*)&lB[r * 128 + (((quad * 2 + 1) ^ k8) << 4)];
      bf[i] = __builtin_shufflevector(lo, hi, 0, 1, 2, 3, 4, 5, 6, 7);
    }

    // MFMA cluster (compiler inserts fine-grained lgkmcnt per operand)
    __builtin_amdgcn_s_setprio(1);
#pragma unroll
    for (int i = 0; i < 4; ++i)
#pragma unroll
      for (int jn = 0; jn < 4; ++jn)
        acc[i][jn] = __builtin_amdgcn_mfma_scale_f32_16x16x128_f8f6f4(
            af[i], bf[jn], acc[i][jn], 0, 0, 0, 127, 0, 127);
    __builtin_amdgcn_s_setprio(0);

    // T4 counted drain: tile t+1 ready; only A(t+2) (4 loads) stays in flight
    if (t + 2 < T)      asm volatile("s_waitcnt vmcnt(4)" ::: "memory");
    else if (t + 1 < T) asm volatile("s_waitcnt vmcnt(0)" ::: "memory");
    __builtin_amdgcn_sched_barrier(0);
    __builtin_amdgcn_s_barrier();

    ab = (ab == 2) ? 0 : ab + 1;
    bb ^= 1;
  }

  // epilogue: C/D layout col=lane&15, row=quad*4+reg (verified r1)
  const float sc = wscale[0] * iscale[0];
  const int rq = quad * 4;
#pragma unroll
  for (int ni = 0; ni < 4; ++ni) {
    const int col = bn * 128 + wn_i * 64 + ni * 16 + r15;
    const float bv = bias[col];
#pragma unroll
    for (int mi = 0; mi < 4; ++mi) {
      const int row = bm * 256 + wm_i * 64 + mi * 16 + rq;
      float* o = out + (size_t)row * N + col;
#pragma unroll
      for (int r = 0; r < 4; ++r)
        o[(size_t)r * N] = acc[mi][ni][r] * sc + bv;
    }
  }
#undef STAGE_A
#undef STAGE_B
}

// ---------------------------------------------------------------------------
extern "C" void kernel_launch(void* const* d_in, const int* in_sizes, int n_in,
                              void* d_out, int out_size, void* d_ws,
                              size_t ws_size, hipStream_t stream) {
  const float*   x      = (const float*)d_in[0];   // f32 [M,K]
  const uint8_t* qw     = (const uint8_t*)d_in[1]; // detected per-call [N,K]
  const float*   wscale = (const float*)d_in[2];   // f32 scalar
  const float*   iscale = (const float*)d_in[3];   // f32 scalar
  const float*   bias   = (const float*)d_in[4];   // f32 [N]
  float*         out    = (float*)d_out;

  const int N = in_sizes[4];          // 2048
  const int K = in_sizes[1] / N;      // 2048
  const int M = in_sizes[0] / K;      // 16384

  // ws layout: [0, M*K) qx fp8 ; [+, N*K) w8 fp8
  uint8_t* qx = (uint8_t*)d_ws;
  uint8_t* w8 = qx + (size_t)M * K;

  const int nx4 = in_sizes[0] / 4;
  quantize_x_kernel<<<(nx4 + 255) / 256, 256, 0, stream>>>(
      (const float4*)x, iscale, (uint32_t*)qx, nx4);

  const int nw4 = in_sizes[1] / 4;
  prep_w_kernel<<<(nw4 + 255) / 256, 256, 0, stream>>>(qw, (uint32_t*)w8, nw4);

  dim3 grid(N / 128, M / 256);
  gemm_fp8_kernel<<<grid, 512, 0, stream>>>(qx, w8, wscale, iscale, bias,
                                            out, M, N, K);
}